// Round 1
// baseline (929.869 us; speedup 1.0000x reference)
//
#include <hip/hip_runtime.h>
#include <hip/hip_bf16.h>
#include <math.h>

// ---------------------------------------------------------------------------
// GraphSAGE 3-layer, HIDDEN=64, mean aggregation.
// out = elu( mean_agg(h) @ W_l + b_l + h @ W_r ) per layer.
// Trick: mean_agg commutes with the linear =>
//   y = [ h@W_l | h@W_r ]  (dense GEMM, coalesced)
//   out[n] = elu( inv_deg[n] * sum_{s in N(n)} y[s][0:64] + b_l + y[n][64:128] )
// CSR (dst-sorted edge list) built once per launch; reused by all 3 layers.
// ---------------------------------------------------------------------------

#define HID 64

// ---- CSR build ------------------------------------------------------------

__global__ void count_deg(const int* __restrict__ dst, int* __restrict__ cnt, int E) {
    int e = blockIdx.x * blockDim.x + threadIdx.x;
    if (e < E) atomicAdd(&cnt[dst[e]], 1);
}

// single-block exclusive scan over cnt[0..n) -> offs[0..n], plus inv_deg
__global__ void scan_offsets(const int* __restrict__ cnt, int* __restrict__ offs,
                             float* __restrict__ invd, int n) {
    __shared__ int psum[1024];
    int t = threadIdx.x;
    int C = (n + 1023) >> 10;          // elements per thread
    int lo = t * C, hi = min(lo + C, n);
    int s = 0;
    for (int i = lo; i < hi; ++i) s += cnt[i];
    psum[t] = s;
    __syncthreads();
    // Hillis-Steele inclusive scan over 1024 partials
    for (int off = 1; off < 1024; off <<= 1) {
        int v = 0;
        if (t >= off) v = psum[t - off];
        __syncthreads();
        psum[t] += v;
        __syncthreads();
    }
    int run = (t == 0) ? 0 : psum[t - 1];
    for (int i = lo; i < hi; ++i) {
        offs[i] = run;
        int c = cnt[i];
        invd[i] = 1.0f / (float)max(c, 1);
        run += c;
    }
    if (hi == n && lo < n) offs[n] = run;   // == E
}

__global__ void fill_csr(const int* __restrict__ src, const int* __restrict__ dst,
                         int* __restrict__ cursor, const int* __restrict__ offs,
                         int* __restrict__ csr, int E) {
    int e = blockIdx.x * blockDim.x + threadIdx.x;
    if (e < E) {
        int d = dst[e];
        int p = atomicAdd(&cursor[d], 1);
        csr[offs[d] + p] = src[e];
    }
}

// ---- dense GEMM: y[n][0:64] = h[n]@W_l ; y[n][64:128] = h[n]@W_r ----------
// 32-row tile per block, 256 threads, 4x4 register tile per thread.

__launch_bounds__(256)
__global__ void gemm_y(const float* __restrict__ h, const float* __restrict__ Wl,
                       const float* __restrict__ Wr, float* __restrict__ y, int nrows) {
    __shared__ float W_s[64][128];      // 32 KB, cols 0..63 = W_l, 64..127 = W_r
    __shared__ float h_s[32][68];       // 68 pad: keeps 16B align + kills bank conflicts
    int tid = threadIdx.x;

    // stage W (coalesced: consecutive tid -> consecutive c)
    for (int idx = tid; idx < 64 * 128; idx += 256) {
        int f = idx >> 7, c = idx & 127;
        W_s[f][c] = (c < 64) ? Wl[f * 64 + c] : Wr[f * 64 + (c - 64)];
    }

    int n0 = blockIdx.x * 32;
    int r  = tid >> 3;                  // 0..31
    int f0 = (tid & 7) * 8;             // 0..56
    float4 v0 = make_float4(0.f, 0.f, 0.f, 0.f), v1 = v0;
    if (n0 + r < nrows) {
        const float4* hp = (const float4*)&h[(size_t)(n0 + r) * HID + f0];
        v0 = hp[0]; v1 = hp[1];
    }
    *(float4*)&h_s[r][f0]     = v0;
    *(float4*)&h_s[r][f0 + 4] = v1;
    __syncthreads();

    int cg = tid & 31, rg = tid >> 5;
    int c0 = cg * 4, r0 = rg * 4;
    float acc[4][4] = {};
#pragma unroll
    for (int f = 0; f < 64; ++f) {
        float4 w = *(const float4*)&W_s[f][c0];
        float h0 = h_s[r0 + 0][f];
        float h1 = h_s[r0 + 1][f];
        float h2 = h_s[r0 + 2][f];
        float h3 = h_s[r0 + 3][f];
        acc[0][0] += h0 * w.x; acc[0][1] += h0 * w.y; acc[0][2] += h0 * w.z; acc[0][3] += h0 * w.w;
        acc[1][0] += h1 * w.x; acc[1][1] += h1 * w.y; acc[1][2] += h1 * w.z; acc[1][3] += h1 * w.w;
        acc[2][0] += h2 * w.x; acc[2][1] += h2 * w.y; acc[2][2] += h2 * w.z; acc[2][3] += h2 * w.w;
        acc[3][0] += h3 * w.x; acc[3][1] += h3 * w.y; acc[3][2] += h3 * w.z; acc[3][3] += h3 * w.w;
    }
#pragma unroll
    for (int i = 0; i < 4; ++i) {
        if (n0 + r0 + i < nrows) {
            float4 o = make_float4(acc[i][0], acc[i][1], acc[i][2], acc[i][3]);
            *(float4*)&y[(size_t)(n0 + r0 + i) * 128 + c0] = o;
        }
    }
}

// ---- aggregate + bias + ELU ----------------------------------------------
// one wave per node; lane = feature

__launch_bounds__(256)
__global__ void sage_aggregate(const float* __restrict__ y, const int* __restrict__ offs,
                               const int* __restrict__ csr, const float* __restrict__ invd,
                               const float* __restrict__ bl, float* __restrict__ out,
                               int nnodes) {
    int lane = threadIdx.x & 63;
    int wid  = blockIdx.x * 4 + (threadIdx.x >> 6);
    int nw   = gridDim.x * 4;
    for (int n = wid; n < nnodes; n += nw) {
        int beg = offs[n], end = offs[n + 1];
        float a0 = 0.f, a1 = 0.f, a2 = 0.f, a3 = 0.f;
        int k = beg;
        for (; k + 4 <= end; k += 4) {
            int s0 = csr[k], s1 = csr[k + 1], s2 = csr[k + 2], s3 = csr[k + 3];
            a0 += y[(size_t)s0 * 128 + lane];
            a1 += y[(size_t)s1 * 128 + lane];
            a2 += y[(size_t)s2 * 128 + lane];
            a3 += y[(size_t)s3 * 128 + lane];
        }
        for (; k < end; ++k) a0 += y[(size_t)csr[k] * 128 + lane];
        float rsum = (a0 + a1) + (a2 + a3);
        float rr = rsum * invd[n] + bl[lane] + y[(size_t)n * 128 + 64 + lane];
        out[(size_t)n * HID + lane] = rr > 0.f ? rr : expm1f(rr);
    }
}

// ---- launch ---------------------------------------------------------------

extern "C" void kernel_launch(void* const* d_in, const int* in_sizes, int n_in,
                              void* d_out, int out_size, void* d_ws, size_t ws_size,
                              hipStream_t stream) {
    const float* x   = (const float*)d_in[0];
    const int*   ei  = (const int*)d_in[1];
    const float* Wl1 = (const float*)d_in[2];
    const float* bl1 = (const float*)d_in[3];
    const float* Wr1 = (const float*)d_in[4];
    const float* Wl2 = (const float*)d_in[5];
    const float* bl2 = (const float*)d_in[6];
    const float* Wr2 = (const float*)d_in[7];
    const float* Wl3 = (const float*)d_in[8];
    const float* bl3 = (const float*)d_in[9];
    const float* Wr3 = (const float*)d_in[10];
    float* out = (float*)d_out;

    int N = in_sizes[0] / HID;   // 100000
    int E = in_sizes[1] / 2;     // 1600000
    const int* src = ei;         // edge_index[0]
    const int* dst = ei + E;     // edge_index[1]

    // workspace layout
    char* p = (char*)d_ws;
    float* y      = (float*)p; p += (size_t)N * 128 * sizeof(float);   // 51.2 MB
    float* hbuf   = (float*)p; p += (size_t)N * HID * sizeof(float);   // 25.6 MB
    int*   csr    = (int*)p;   p += (size_t)E * sizeof(int);           // 6.4 MB
    int*   cnt    = (int*)p;   p += (size_t)N * sizeof(int);
    int*   cursor = (int*)p;   p += (size_t)N * sizeof(int);           // adjacent to cnt
    int*   offs   = (int*)p;   p += (size_t)(N + 1) * sizeof(int);
    float* invd   = (float*)p; p += (size_t)N * sizeof(float);

    // zero cnt + cursor in one memset (they are adjacent)
    hipMemsetAsync(cnt, 0, (size_t)N * 2 * sizeof(int), stream);

    int eb = (E + 255) / 256;
    count_deg<<<eb, 256, 0, stream>>>(dst, cnt, E);
    scan_offsets<<<1, 1024, 0, stream>>>(cnt, offs, invd, N);
    fill_csr<<<eb, 256, 0, stream>>>(src, dst, cursor, offs, csr, E);

    struct Layer { const float* Wl; const float* bl; const float* Wr; };
    Layer L[3] = {{Wl1, bl1, Wr1}, {Wl2, bl2, Wr2}, {Wl3, bl3, Wr3}};

    const float* hin = x;
    int gb = (N + 31) / 32;   // 3125
    for (int l = 0; l < 3; ++l) {
        gemm_y<<<gb, 256, 0, stream>>>(hin, L[l].Wl, L[l].Wr, y, N);
        float* hout = (l == 2) ? out : hbuf;
        sage_aggregate<<<2048, 256, 0, stream>>>(y, offs, csr, invd, L[l].bl, hout, N);
        hin = hbuf;
    }
}

// Round 3
// 687.567 us; speedup vs baseline: 1.3524x; 1.3524x over previous
//
#include <hip/hip_runtime.h>
#include <hip/hip_bf16.h>
#include <math.h>

// ---------------------------------------------------------------------------
// GraphSAGE 3-layer, HIDDEN=64, mean aggregation.
// out = elu( mean_agg(h) @ W_l + b_l + h @ W_r ) per layer.
// Trick: mean_agg commutes with the linear =>
//   y = [ h@W_l | h@W_r ]  (dense GEMM, coalesced)
//   out[n] = elu( inv_deg[n] * sum_{s in N(n)} y[s][0:64] + b_l + y[n][64:128] )
// CSR (dst-sorted edge list) built once per launch; reused by all 3 layers.
// R2: replaced single-block scan (226us, 0.15% occupancy) with 3-kernel
//     multi-block scan (coalesced int4, ~98 blocks).
// R3: identical resubmit (R2 bench hit GPUAcquisitionTimeout, never ran).
// ---------------------------------------------------------------------------

#define HID 64

// ---- CSR build ------------------------------------------------------------

__global__ void count_deg(const int* __restrict__ dst, int* __restrict__ cnt, int E) {
    int e = blockIdx.x * blockDim.x + threadIdx.x;
    if (e < E) atomicAdd(&cnt[dst[e]], 1);
}

// pass 1: per-block sums of 1024 counts (256 thr x int4)
__global__ void scan_partials(const int* __restrict__ cnt, int* __restrict__ bsum, int n) {
    __shared__ int lsum[256];
    int t = threadIdx.x;
    int base = blockIdx.x * 1024 + t * 4;
    int s = 0;
    if (base + 3 < n) {
        int4 v = *(const int4*)&cnt[base];
        s = v.x + v.y + v.z + v.w;
    } else {
        for (int i = 0; i < 4; ++i) if (base + i < n) s += cnt[base + i];
    }
    lsum[t] = s;
    __syncthreads();
    for (int off = 128; off > 0; off >>= 1) {
        if (t < off) lsum[t] += lsum[t + off];
        __syncthreads();
    }
    if (t == 0) bsum[blockIdx.x] = lsum[0];
}

// pass 2: exclusive scan of block sums (nb <= 128), write offs[N]=E
__global__ void scan_tops(int* __restrict__ bsum, int* __restrict__ offs_last,
                          int nb, int E) {
    __shared__ int s[128];
    int t = threadIdx.x;
    s[t] = (t < nb) ? bsum[t] : 0;
    __syncthreads();
    for (int off = 1; off < 128; off <<= 1) {
        int v = (t >= off) ? s[t - off] : 0;
        __syncthreads();
        s[t] += v;
        __syncthreads();
    }
    if (t < nb) bsum[t] = (t == 0) ? 0 : s[t - 1];
    if (t == 0) *offs_last = E;   // offs[N] == E by construction
}

// pass 3: per-element exclusive offsets + inv_deg
__global__ void scan_write(const int* __restrict__ cnt, const int* __restrict__ bsum,
                           int* __restrict__ offs, float* __restrict__ invd, int n) {
    __shared__ int lsum[256];
    int t = threadIdx.x;
    int base = blockIdx.x * 1024 + t * 4;
    int v0 = 0, v1 = 0, v2 = 0, v3 = 0;
    bool full = (base + 3 < n);
    if (full) {
        int4 v = *(const int4*)&cnt[base];
        v0 = v.x; v1 = v.y; v2 = v.z; v3 = v.w;
    } else {
        if (base     < n) v0 = cnt[base];
        if (base + 1 < n) v1 = cnt[base + 1];
        if (base + 2 < n) v2 = cnt[base + 2];
        if (base + 3 < n) v3 = cnt[base + 3];
    }
    int ts = v0 + v1 + v2 + v3;
    lsum[t] = ts;
    __syncthreads();
    for (int off = 1; off < 256; off <<= 1) {
        int u = (t >= off) ? lsum[t - off] : 0;
        __syncthreads();
        lsum[t] += u;
        __syncthreads();
    }
    int ex = bsum[blockIdx.x] + ((t == 0) ? 0 : lsum[t - 1]);
    int o0 = ex, o1 = ex + v0, o2 = o1 + v1, o3 = o2 + v2;
    if (full) {
        *(int4*)&offs[base] = make_int4(o0, o1, o2, o3);
        float4 f = make_float4(1.0f / (float)max(v0, 1), 1.0f / (float)max(v1, 1),
                               1.0f / (float)max(v2, 1), 1.0f / (float)max(v3, 1));
        *(float4*)&invd[base] = f;
    } else {
        if (base     < n) { offs[base]     = o0; invd[base]     = 1.0f / (float)max(v0, 1); }
        if (base + 1 < n) { offs[base + 1] = o1; invd[base + 1] = 1.0f / (float)max(v1, 1); }
        if (base + 2 < n) { offs[base + 2] = o2; invd[base + 2] = 1.0f / (float)max(v2, 1); }
        if (base + 3 < n) { offs[base + 3] = o3; invd[base + 3] = 1.0f / (float)max(v3, 1); }
    }
}

__global__ void fill_csr(const int* __restrict__ src, const int* __restrict__ dst,
                         int* __restrict__ cursor, const int* __restrict__ offs,
                         int* __restrict__ csr, int E) {
    int e = blockIdx.x * blockDim.x + threadIdx.x;
    if (e < E) {
        int d = dst[e];
        int p = atomicAdd(&cursor[d], 1);
        csr[offs[d] + p] = src[e];
    }
}

// ---- dense GEMM: y[n][0:64] = h[n]@W_l ; y[n][64:128] = h[n]@W_r ----------

__launch_bounds__(256)
__global__ void gemm_y(const float* __restrict__ h, const float* __restrict__ Wl,
                       const float* __restrict__ Wr, float* __restrict__ y, int nrows) {
    __shared__ float W_s[64][128];
    __shared__ float h_s[32][68];
    int tid = threadIdx.x;

    for (int idx = tid; idx < 64 * 128; idx += 256) {
        int f = idx >> 7, c = idx & 127;
        W_s[f][c] = (c < 64) ? Wl[f * 64 + c] : Wr[f * 64 + (c - 64)];
    }

    int n0 = blockIdx.x * 32;
    int r  = tid >> 3;
    int f0 = (tid & 7) * 8;
    float4 v0 = make_float4(0.f, 0.f, 0.f, 0.f), v1 = v0;
    if (n0 + r < nrows) {
        const float4* hp = (const float4*)&h[(size_t)(n0 + r) * HID + f0];
        v0 = hp[0]; v1 = hp[1];
    }
    *(float4*)&h_s[r][f0]     = v0;
    *(float4*)&h_s[r][f0 + 4] = v1;
    __syncthreads();

    int cg = tid & 31, rg = tid >> 5;
    int c0 = cg * 4, r0 = rg * 4;
    float acc[4][4] = {};
#pragma unroll
    for (int f = 0; f < 64; ++f) {
        float4 w = *(const float4*)&W_s[f][c0];
        float h0 = h_s[r0 + 0][f];
        float h1 = h_s[r0 + 1][f];
        float h2 = h_s[r0 + 2][f];
        float h3 = h_s[r0 + 3][f];
        acc[0][0] += h0 * w.x; acc[0][1] += h0 * w.y; acc[0][2] += h0 * w.z; acc[0][3] += h0 * w.w;
        acc[1][0] += h1 * w.x; acc[1][1] += h1 * w.y; acc[1][2] += h1 * w.z; acc[1][3] += h1 * w.w;
        acc[2][0] += h2 * w.x; acc[2][1] += h2 * w.y; acc[2][2] += h2 * w.z; acc[2][3] += h2 * w.w;
        acc[3][0] += h3 * w.x; acc[3][1] += h3 * w.y; acc[3][2] += h3 * w.z; acc[3][3] += h3 * w.w;
    }
#pragma unroll
    for (int i = 0; i < 4; ++i) {
        if (n0 + r0 + i < nrows) {
            float4 o = make_float4(acc[i][0], acc[i][1], acc[i][2], acc[i][3]);
            *(float4*)&y[(size_t)(n0 + r0 + i) * 128 + c0] = o;
        }
    }
}

// ---- aggregate + bias + ELU ----------------------------------------------

__launch_bounds__(256)
__global__ void sage_aggregate(const float* __restrict__ y, const int* __restrict__ offs,
                               const int* __restrict__ csr, const float* __restrict__ invd,
                               const float* __restrict__ bl, float* __restrict__ out,
                               int nnodes) {
    int lane = threadIdx.x & 63;
    int wid  = blockIdx.x * 4 + (threadIdx.x >> 6);
    int nw   = gridDim.x * 4;
    for (int n = wid; n < nnodes; n += nw) {
        int beg = offs[n], end = offs[n + 1];
        float a0 = 0.f, a1 = 0.f, a2 = 0.f, a3 = 0.f;
        int k = beg;
        for (; k + 4 <= end; k += 4) {
            int s0 = csr[k], s1 = csr[k + 1], s2 = csr[k + 2], s3 = csr[k + 3];
            a0 += y[(size_t)s0 * 128 + lane];
            a1 += y[(size_t)s1 * 128 + lane];
            a2 += y[(size_t)s2 * 128 + lane];
            a3 += y[(size_t)s3 * 128 + lane];
        }
        for (; k < end; ++k) a0 += y[(size_t)csr[k] * 128 + lane];
        float rsum = (a0 + a1) + (a2 + a3);
        float rr = rsum * invd[n] + bl[lane] + y[(size_t)n * 128 + 64 + lane];
        out[(size_t)n * HID + lane] = rr > 0.f ? rr : expm1f(rr);
    }
}

// ---- launch ---------------------------------------------------------------

extern "C" void kernel_launch(void* const* d_in, const int* in_sizes, int n_in,
                              void* d_out, int out_size, void* d_ws, size_t ws_size,
                              hipStream_t stream) {
    const float* x   = (const float*)d_in[0];
    const int*   ei  = (const int*)d_in[1];
    const float* Wl1 = (const float*)d_in[2];
    const float* bl1 = (const float*)d_in[3];
    const float* Wr1 = (const float*)d_in[4];
    const float* Wl2 = (const float*)d_in[5];
    const float* bl2 = (const float*)d_in[6];
    const float* Wr2 = (const float*)d_in[7];
    const float* Wl3 = (const float*)d_in[8];
    const float* bl3 = (const float*)d_in[9];
    const float* Wr3 = (const float*)d_in[10];
    float* out = (float*)d_out;

    int N = in_sizes[0] / HID;   // 100000
    int E = in_sizes[1] / 2;     // 1600000
    const int* src = ei;
    const int* dst = ei + E;

    // workspace layout (all 16B aligned)
    char* p = (char*)d_ws;
    float* y      = (float*)p; p += (size_t)N * 128 * sizeof(float);
    float* hbuf   = (float*)p; p += (size_t)N * HID * sizeof(float);
    int*   csr    = (int*)p;   p += (size_t)E * sizeof(int);
    int*   cnt    = (int*)p;   p += (size_t)N * sizeof(int);
    int*   cursor = (int*)p;   p += (size_t)N * sizeof(int);   // adjacent to cnt
    int*   offs   = (int*)p;   p += (size_t)(N + 4) * sizeof(int);
    float* invd   = (float*)p; p += (size_t)N * sizeof(float);
    int*   bsum   = (int*)p;   p += 256 * sizeof(int);

    hipMemsetAsync(cnt, 0, (size_t)N * 2 * sizeof(int), stream);

    int eb = (E + 255) / 256;
    int sb = (N + 1023) / 1024;   // 98 scan blocks
    count_deg<<<eb, 256, 0, stream>>>(dst, cnt, E);
    scan_partials<<<sb, 256, 0, stream>>>(cnt, bsum, N);
    scan_tops<<<1, 128, 0, stream>>>(bsum, &offs[N], sb, E);
    scan_write<<<sb, 256, 0, stream>>>(cnt, bsum, offs, invd, N);
    fill_csr<<<eb, 256, 0, stream>>>(src, dst, cursor, offs, csr, E);

    struct Layer { const float* Wl; const float* bl; const float* Wr; };
    Layer L[3] = {{Wl1, bl1, Wr1}, {Wl2, bl2, Wr2}, {Wl3, bl3, Wr3}};

    const float* hin = x;
    int gb = (N + 31) / 32;
    for (int l = 0; l < 3; ++l) {
        gemm_y<<<gb, 256, 0, stream>>>(hin, L[l].Wl, L[l].Wr, y, N);
        float* hout = (l == 2) ? out : hbuf;
        sage_aggregate<<<2048, 256, 0, stream>>>(y, offs, csr, invd, L[l].bl, hout, N);
        hin = hbuf;
    }
}